// Round 2
// baseline (1119.278 us; speedup 1.0000x reference)
//
#include <hip/hip_runtime.h>
#include <cstdint>
#include <cstddef>

// MatchNet pipeline on MI355X (gfx950), round 1 (resubmit of round-0 baseline;
// previous round hit GPUAcquisitionTimeout — no signal).
//
//  conv(3x3,s2,p1)+ReLU  -> implicit-im2col GEMM  M=50176 K=2304 N=256 -> x_b bf16 [1024][12544]
//  FC1+ReLU              -> GEMM                  M=1024  K=12544 N=1024 -> h_b bf16
//  FC2                   -> GEMM                  M=1024  K=1024  N=256  -> e fp32
//  L2-normalize rows     -> e_b bf16
//  pairwise |ei-ej|@wm+bm over triu(i<j)          -> logits fp32 [523776]
//
// GEMM: 64x64 block tile, 4 waves (2x2), each wave 32x32 via 2x2 mfma_f32_16x16x32_bf16 frags.
// Weights pre-transposed to Bt[N][K] bf16 so A/B frag loads are contiguous b128 from LDS.
// ws layout (57 MB total): x_b | w1t | h_b | w2t | cwb | e | e_b

using u16 = unsigned short;
using u32 = unsigned int;
typedef __attribute__((ext_vector_type(8))) short bf16x8;
typedef __attribute__((ext_vector_type(4))) float f32x4;
typedef __attribute__((ext_vector_type(4))) int i32x4;

__device__ __forceinline__ u16 f2bf(float f) {
    u32 u = __float_as_uint(f);
    u32 r = (u + 0x7FFFu + ((u >> 16) & 1u)) >> 16;   // RNE
    return (u16)r;
}
__device__ __forceinline__ float bf2f(u16 h) {
    return __uint_as_float(((u32)h) << 16);
}

// ---------- elementwise cast fp32 -> bf16 ----------
__global__ __launch_bounds__(256) void cast_kernel(const float* __restrict__ in,
                                                   u16* __restrict__ out, int n) {
    int i = blockIdx.x * 256 + threadIdx.x;
    if (i < n) out[i] = f2bf(in[i]);
}

// ---------- transpose + cast: in fp32 [R][C] -> out bf16 [C][R]; R,C % 32 == 0 ----------
__global__ __launch_bounds__(256) void transpose_cast_kernel(const float* __restrict__ in,
                                                             u16* __restrict__ out,
                                                             int R, int C) {
    __shared__ float t[32][33];
    int tx = threadIdx.x & 31, ty = threadIdx.x >> 5;  // 32 x 8
    int r0 = blockIdx.y * 32, c0 = blockIdx.x * 32;
#pragma unroll
    for (int p = 0; p < 4; ++p)
        t[ty + p * 8][tx] = in[(size_t)(r0 + ty + p * 8) * C + c0 + tx];
    __syncthreads();
#pragma unroll
    for (int p = 0; p < 4; ++p)
        out[(size_t)(c0 + ty + p * 8) * R + r0 + tx] = f2bf(t[tx][ty + p * 8]);
}

// ---------- shared GEMM: C[M][N] = A[M][K] @ Bt[N][K]^T, bf16 in, fp32 acc ----------
// MODE 0: conv (implicit im2col A from features, epilogue +bias,ReLU -> x_b scatter)
// MODE 1: FC1  (epilogue +bias,ReLU -> bf16 row-major)
// MODE 2: FC2  (epilogue +bias -> fp32 row-major)
template <int MODE>
__global__ __launch_bounds__(256) void gemm_kernel(
    const float* __restrict__ features,  // MODE 0
    const u16* __restrict__ A,           // MODE 1/2
    const u16* __restrict__ Bt,          // [N][K]
    const float* __restrict__ bias,      // [N]
    void* __restrict__ out,
    int M, int N, int K)
{
    __shared__ u16 lA[64 * 32];
    __shared__ u16 lB[64 * 32];
    const int tid = threadIdx.x;
    const int lane = tid & 63;
    const int wv = tid >> 6;
    const int wmi = wv >> 1, wni = wv & 1;   // wave 2x2 grid
    const int g = lane >> 4, ln = lane & 15; // frag lane decomposition
    const int bm0 = blockIdx.y * 64, bn0 = blockIdx.x * 64;

    const int srow = tid >> 2;  // staging row 0..63
    const int sseg = tid & 3;   // 8-elem segment 0..3

    // conv: per-thread constant output position for the staged A row
    int cn = 0, coy = 0, cox = 0;
    if (MODE == 0) {
        int m = bm0 + srow;
        cn = m / 49;
        int s = m - cn * 49;
        coy = s / 7;
        cox = s - coy * 7;
    }

    f32x4 acc[2][2] = {};

    for (int k0 = 0; k0 < K; k0 += 32) {
        if (MODE == 0) {
            // implicit im2col: k = c*9 + ky*3 + kx  (matches conv_w [oc][c][ky][kx] flat)
#pragma unroll
            for (int i = 0; i < 8; ++i) {
                int kk = sseg * 8 + i;
                int k = k0 + kk;
                int c = k / 9;
                int r = k - c * 9;
                int ky = r / 3;
                int kx = r - ky * 3;
                int iy = coy * 2 - 1 + ky;
                int ix = cox * 2 - 1 + kx;
                float v = 0.f;
                if ((unsigned)iy < 14u && (unsigned)ix < 14u)
                    v = features[(size_t)(cn * 256 + c) * 196 + iy * 14 + ix];
                lA[srow * 32 + kk] = f2bf(v);
            }
        } else {
            *(i32x4*)&lA[srow * 32 + sseg * 8] =
                *(const i32x4*)&A[(size_t)(bm0 + srow) * K + k0 + sseg * 8];
        }
        *(i32x4*)&lB[srow * 32 + sseg * 8] =
            *(const i32x4*)&Bt[(size_t)(bn0 + srow) * K + k0 + sseg * 8];
        __syncthreads();

        bf16x8 aF[2], bF[2];
#pragma unroll
        for (int mf = 0; mf < 2; ++mf)
            aF[mf] = *(const bf16x8*)&lA[(wmi * 32 + mf * 16 + ln) * 32 + g * 8];
#pragma unroll
        for (int nf = 0; nf < 2; ++nf)
            bF[nf] = *(const bf16x8*)&lB[(wni * 32 + nf * 16 + ln) * 32 + g * 8];
#pragma unroll
        for (int mf = 0; mf < 2; ++mf)
#pragma unroll
            for (int nf = 0; nf < 2; ++nf)
                acc[mf][nf] = __builtin_amdgcn_mfma_f32_16x16x32_bf16(
                    aF[mf], bF[nf], acc[mf][nf], 0, 0, 0);
        __syncthreads();
    }

    // epilogue: D row = (lane>>4)*4 + r, col = lane&15  (m89-verified layout)
#pragma unroll
    for (int mf = 0; mf < 2; ++mf) {
#pragma unroll
        for (int nf = 0; nf < 2; ++nf) {
#pragma unroll
            for (int r = 0; r < 4; ++r) {
                int grow = bm0 + wmi * 32 + mf * 16 + g * 4 + r;
                int gcol = bn0 + wni * 32 + nf * 16 + ln;
                float v = acc[mf][nf][r] + bias[gcol];
                if (MODE == 0) {
                    v = fmaxf(v, 0.f);
                    int n = grow / 49, s = grow - n * 49;
                    ((u16*)out)[(size_t)n * 12544 + gcol * 49 + s] = f2bf(v);
                } else if (MODE == 1) {
                    v = fmaxf(v, 0.f);
                    ((u16*)out)[(size_t)grow * 1024 + gcol] = f2bf(v);
                } else {
                    ((float*)out)[(size_t)grow * 256 + gcol] = v;
                }
            }
        }
    }
}

// ---------- row L2-normalize: e fp32 [1024][256] -> e_b bf16 ----------
__global__ __launch_bounds__(256) void normalize_kernel(const float* __restrict__ e,
                                                        u16* __restrict__ eb) {
    __shared__ float sw[4];
    int row = blockIdx.x, tid = threadIdx.x;
    float v = e[row * 256 + tid];
    float ss = v * v;
#pragma unroll
    for (int m = 32; m; m >>= 1) ss += __shfl_xor(ss, m, 64);
    if ((tid & 63) == 0) sw[tid >> 6] = ss;
    __syncthreads();
    float tot = sw[0] + sw[1] + sw[2] + sw[3];
    float inv = 1.0f / sqrtf(tot);
    eb[row * 256 + tid] = f2bf(v * inv);
}

// ---------- pairwise logits: out[p(i,j)] = sum_k wm[k]*|e[i][k]-e[j][k]| + bm ----------
__global__ __launch_bounds__(256) void pairwise_kernel(const u16* __restrict__ eb,
                                                       const float* __restrict__ wm,
                                                       const float* __restrict__ bmp,
                                                       float* __restrict__ out) {
    int ib = blockIdx.y, jb = blockIdx.x;
    if (jb < ib) return;
    __shared__ u16 sI[64 * 256];
    __shared__ u16 sJ[64 * 256];
    __shared__ float swm[256];
    int tid = threadIdx.x;
    {
        const i32x4* srcI = (const i32x4*)(eb + (size_t)ib * 64 * 256);
        const i32x4* srcJ = (const i32x4*)(eb + (size_t)jb * 64 * 256);
        i32x4* dI = (i32x4*)sI;
        i32x4* dJ = (i32x4*)sJ;
#pragma unroll
        for (int q = 0; q < 8; ++q) {
            dI[q * 256 + tid] = srcI[q * 256 + tid];
            dJ[q * 256 + tid] = srcJ[q * 256 + tid];
        }
        swm[tid] = wm[tid];
    }
    __syncthreads();
    float bmv = bmp[0];
    int tx = tid & 15, ty = tid >> 4;
    float acc[4][4] = {};
    const u32* rI = (const u32*)sI;
    const u32* rJ = (const u32*)sJ;
    for (int kk = 0; kk < 128; ++kk) {
        float w0 = swm[kk * 2], w1 = swm[kk * 2 + 1];
        float li[4], hi[4], lj[4], hj[4];
#pragma unroll
        for (int a = 0; a < 4; ++a) {
            u32 u = rI[(ty * 4 + a) * 128 + kk];
            li[a] = __uint_as_float(u << 16);
            hi[a] = __uint_as_float(u & 0xFFFF0000u);
        }
#pragma unroll
        for (int b = 0; b < 4; ++b) {
            u32 u = rJ[(tx * 4 + b) * 128 + kk];
            lj[b] = __uint_as_float(u << 16);
            hj[b] = __uint_as_float(u & 0xFFFF0000u);
        }
#pragma unroll
        for (int a = 0; a < 4; ++a)
#pragma unroll
            for (int b = 0; b < 4; ++b)
                acc[a][b] += w0 * fabsf(li[a] - lj[b]) + w1 * fabsf(hi[a] - hj[b]);
    }
#pragma unroll
    for (int a = 0; a < 4; ++a) {
        int i = ib * 64 + ty * 4 + a;
#pragma unroll
        for (int b = 0; b < 4; ++b) {
            int j = jb * 64 + tx * 4 + b;
            if (j > i) {
                int p = i * (2047 - i) / 2 + (j - i - 1);
                out[p] = acc[a][b] + bmv;
            }
        }
    }
}

extern "C" void kernel_launch(void* const* d_in, const int* in_sizes, int n_in,
                              void* d_out, int out_size, void* d_ws, size_t ws_size,
                              hipStream_t stream) {
    const float* features = (const float*)d_in[0];
    // d_in[1] = ids (unused by reference)
    const float* conv_w = (const float*)d_in[2];
    const float* conv_b = (const float*)d_in[3];
    const float* w1 = (const float*)d_in[4];
    const float* b1 = (const float*)d_in[5];
    const float* w2 = (const float*)d_in[6];
    const float* b2 = (const float*)d_in[7];
    const float* wm = (const float*)d_in[8];
    const float* bm = (const float*)d_in[9];
    float* logits = (float*)d_out;

    char* ws = (char*)d_ws;
    u16* x_b = (u16*)(ws);                  // 1024*12544 bf16 = 25,690,112 B
    u16* w1t = (u16*)(ws + 25690112);       // 1024*12544 bf16
    u16* h_b = (u16*)(ws + 51380224);       // 1024*1024 bf16
    u16* w2t = (u16*)(ws + 53477376);       // 256*1024 bf16
    u16* cwb = (u16*)(ws + 54001664);       // 256*2304 bf16
    float* e = (float*)(ws + 55181312);     // 1024*256 fp32
    u16* e_b = (u16*)(ws + 56229888);       // 1024*256 bf16  (end: 56,754,176 B)

    // weight prep
    cast_kernel<<<2304, 256, 0, stream>>>(conv_w, cwb, 256 * 2304);
    transpose_cast_kernel<<<dim3(32, 392), 256, 0, stream>>>(w1, w1t, 12544, 1024);
    transpose_cast_kernel<<<dim3(8, 32), 256, 0, stream>>>(w2, w2t, 1024, 256);

    // conv as implicit-im2col GEMM: M=50176 (n*49+s), N=256 (oc), K=2304 (c*9+tap)
    gemm_kernel<0><<<dim3(4, 784), 256, 0, stream>>>(features, nullptr, cwb, conv_b,
                                                     x_b, 50176, 256, 2304);
    // FC1: M=1024, N=1024, K=12544
    gemm_kernel<1><<<dim3(16, 16), 256, 0, stream>>>(nullptr, x_b, w1t, b1,
                                                     h_b, 1024, 1024, 12544);
    // FC2: M=1024, N=256, K=1024
    gemm_kernel<2><<<dim3(4, 16), 256, 0, stream>>>(nullptr, h_b, w2t, b2,
                                                    e, 1024, 256, 1024);
    normalize_kernel<<<1024, 256, 0, stream>>>(e, e_b);
    pairwise_kernel<<<dim3(16, 16), 256, 0, stream>>>(e_b, wm, bm, logits);
}

// Round 3
// 674.875 us; speedup vs baseline: 1.6585x; 1.6585x over previous
//
#include <hip/hip_runtime.h>
#include <cstdint>
#include <cstddef>

// MatchNet pipeline on MI355X (gfx950), round 2.
// R1 post-mortem: conv GEMM was 630us, MfmaUtil 4%, VALUBusy 59% -> scalar im2col
// staging in the K-loop dominated. Fix: materialize im2col (tap-major K for
// coalesced writes), m97-structure 128^2 GEMM with global_load_lds(16B),
// split-K=4 FC1, padded pairwise LDS.
//
// ws layout (fixed tail 73.5MB + col chunk, chunk sized from ws_size):
//   x_b | w1t | part | h_b | w2t | cwb | e | e_b | col

using u16 = unsigned short;
using u32 = unsigned int;
typedef __attribute__((ext_vector_type(8))) short bf16x8;
typedef __attribute__((ext_vector_type(4))) float f32x4;
typedef __attribute__((ext_vector_type(4))) int i32x4;

__device__ __forceinline__ u16 f2bf(float f) {
    u32 u = __float_as_uint(f);
    u32 r = (u + 0x7FFFu + ((u >> 16) & 1u)) >> 16;   // RNE
    return (u16)r;
}

__device__ __forceinline__ void gload_lds16(const u16* gsrc, u16* ldst) {
    __builtin_amdgcn_global_load_lds(
        (const __attribute__((address_space(1))) u32*)gsrc,
        (__attribute__((address_space(3))) u32*)ldst,
        16, 0, 0);
}

// ---------- weight reorder: conv_w [oc][c][3][3] fp32 -> cwb [oc][tap*256+c] bf16 ----------
__global__ __launch_bounds__(256) void wreorder_kernel(const float* __restrict__ w,
                                                       u16* __restrict__ out) {
    int idx = blockIdx.x * 256 + threadIdx.x;   // oc*256 + c
    int oc = idx >> 8, c = idx & 255;
    const float* src = w + (size_t)idx * 9;
    u16* dst = out + (size_t)oc * 2304 + c;
#pragma unroll
    for (int t = 0; t < 9; ++t) dst[t * 256] = f2bf(src[t]);
}

// ---------- transpose + cast: in fp32 [R][C] -> out bf16 [C][R]; R,C % 32 == 0 ----------
__global__ __launch_bounds__(256) void transpose_cast_kernel(const float* __restrict__ in,
                                                             u16* __restrict__ out,
                                                             int R, int C) {
    __shared__ float t[32][33];
    int tx = threadIdx.x & 31, ty = threadIdx.x >> 5;  // 32 x 8
    int r0 = blockIdx.y * 32, c0 = blockIdx.x * 32;
#pragma unroll
    for (int p = 0; p < 4; ++p)
        t[ty + p * 8][tx] = in[(size_t)(r0 + ty + p * 8) * C + c0 + tx];
    __syncthreads();
#pragma unroll
    for (int p = 0; p < 4; ++p)
        out[(size_t)(c0 + ty + p * 8) * R + r0 + tx] = f2bf(t[tx][ty + p * 8]);
}

// ---------- im2col (tap-major): col[m_local][tap*256+c], m=(n,oy,ox) ----------
// block = n_local*7 + oy, thread = c. Writes lane-coalesced (consecutive c).
__global__ __launch_bounds__(256) void im2col_kernel(const float* __restrict__ features,
                                                     u16* __restrict__ col, int n_base) {
    int blk = blockIdx.x;
    int n_local = blk / 7, oy = blk - n_local * 7;
    int n = n_base + n_local;
    int c = threadIdx.x;
    const float* f = features + ((size_t)n * 256 + c) * 196;
    float r[3][16];
#pragma unroll
    for (int dy = 0; dy < 3; ++dy) {
        int iy = oy * 2 - 1 + dy;
        r[dy][0] = 0.f;
        r[dy][15] = 0.f;
        if ((unsigned)iy < 14u) {
            const float* row = f + iy * 14;
#pragma unroll
            for (int x = 0; x < 7; ++x) {
                float2 v = *(const float2*)(row + x * 2);
                r[dy][1 + x * 2] = v.x;
                r[dy][2 + x * 2] = v.y;
            }
        } else {
#pragma unroll
            for (int x = 0; x < 14; ++x) r[dy][1 + x] = 0.f;
        }
    }
    u16* base = col + (size_t)(n_local * 49 + oy * 7) * 2304 + c;
#pragma unroll
    for (int dy = 0; dy < 3; ++dy)
#pragma unroll
        for (int dx = 0; dx < 3; ++dx) {
            int tap = dy * 3 + dx;
#pragma unroll
            for (int ox = 0; ox < 7; ++ox)   // ix+1 = ox*2+dx
                base[(size_t)ox * 2304 + tap * 256] = f2bf(r[dy][ox * 2 + dx]);
        }
}

// ---------- m97-structure GEMM: 128x128 tile, BK=64, global_load_lds, 4 waves 4x4 frags ----
// MODE 0: conv epilogue (+bias, ReLU, bf16 scatter to x_b [n][oc*49+s])
// MODE 1: fc1 split-K partial (fp32, no bias; out += blockIdx.z * 1M elems)
template <int MODE>
__global__ __launch_bounds__(256) void gemm128_kernel(
    const u16* __restrict__ A, int lda,
    const u16* __restrict__ Bt, int ldb,
    const float* __restrict__ bias,
    void* __restrict__ out,
    int m_base, int k_chunk)
{
    __shared__ __align__(16) u16 sA[128 * 64];
    __shared__ __align__(16) u16 sB[128 * 64];
    const int tid = threadIdx.x;
    const int lane = tid & 63;
    const int g = lane >> 4, ln = lane & 15;
    const int wv = tid >> 6;
    const int wm2 = wv >> 1, wn2 = wv & 1;
    const int bm0 = blockIdx.y * 128, bn0 = blockIdx.x * 128;
    const int srow = tid >> 3;          // 0..31
    const int scol = (tid & 7) * 8;     // 0,8,..,56
    const int k_begin = (MODE == 1) ? blockIdx.z * k_chunk : 0;

    const u16* Ab = A + (size_t)bm0 * lda + k_begin;
    const u16* Bb = Bt + (size_t)bn0 * ldb + k_begin;

    f32x4 acc[4][4] = {};

    for (int k0 = 0; k0 < k_chunk; k0 += 64) {
#pragma unroll
        for (int q = 0; q < 4; ++q) {
            int row = q * 32 + srow;
            gload_lds16(Ab + (size_t)row * lda + k0 + scol, &sA[(q * 256 + tid) * 8]);
        }
#pragma unroll
        for (int q = 0; q < 4; ++q) {
            int row = q * 32 + srow;
            gload_lds16(Bb + (size_t)row * ldb + k0 + scol, &sB[(q * 256 + tid) * 8]);
        }
        __syncthreads();
#pragma unroll
        for (int ks = 0; ks < 2; ++ks) {
            bf16x8 aF[4], bF[4];
#pragma unroll
            for (int i = 0; i < 4; ++i)
                aF[i] = *(const bf16x8*)&sA[(wm2 * 64 + i * 16 + ln) * 64 + ks * 32 + g * 8];
#pragma unroll
            for (int i = 0; i < 4; ++i)
                bF[i] = *(const bf16x8*)&sB[(wn2 * 64 + i * 16 + ln) * 64 + ks * 32 + g * 8];
#pragma unroll
            for (int mf = 0; mf < 4; ++mf)
#pragma unroll
                for (int nf = 0; nf < 4; ++nf)
                    acc[mf][nf] = __builtin_amdgcn_mfma_f32_16x16x32_bf16(
                        aF[mf], bF[nf], acc[mf][nf], 0, 0, 0);
        }
        __syncthreads();
    }

    if (MODE == 0) {
        u16* xb = (u16*)out;
#pragma unroll
        for (int mf = 0; mf < 4; ++mf)
#pragma unroll
            for (int nf = 0; nf < 4; ++nf)
#pragma unroll
                for (int r = 0; r < 4; ++r) {
                    int grow = m_base + bm0 + wm2 * 64 + mf * 16 + g * 4 + r;
                    int gcol = bn0 + wn2 * 64 + nf * 16 + ln;
                    float v = fmaxf(acc[mf][nf][r] + bias[gcol], 0.f);
                    int n = grow / 49, s = grow - n * 49;
                    xb[(size_t)n * 12544 + gcol * 49 + s] = f2bf(v);
                }
    } else {
        float* po = (float*)out + (size_t)blockIdx.z * (1024 * 1024);
#pragma unroll
        for (int mf = 0; mf < 4; ++mf)
#pragma unroll
            for (int nf = 0; nf < 4; ++nf)
#pragma unroll
                for (int r = 0; r < 4; ++r) {
                    int grow = bm0 + wm2 * 64 + mf * 16 + g * 4 + r;
                    int gcol = bn0 + wn2 * 64 + nf * 16 + ln;
                    po[(size_t)grow * 1024 + gcol] = acc[mf][nf][r];
                }
    }
}

// ---------- FC1 reduce: sum 4 partials + bias + ReLU -> bf16 ----------
__global__ __launch_bounds__(256) void fc1_reduce_kernel(const float* __restrict__ part,
                                                         const float* __restrict__ b1,
                                                         u16* __restrict__ h) {
    int i = blockIdx.x * 256 + threadIdx.x;
    float v = part[i] + part[i + 1048576] + part[i + 2097152] + part[i + 3145728];
    v = fmaxf(v + b1[i & 1023], 0.f);
    h[i] = f2bf(v);
}

// ---------- FC2: 64x64 tile (M=1024,N=256,K=1024), fp32 out +bias ----------
__global__ __launch_bounds__(256) void gemm64_fc2(const u16* __restrict__ A,
                                                  const u16* __restrict__ Bt,
                                                  const float* __restrict__ bias,
                                                  float* __restrict__ out) {
    __shared__ u16 lA[64 * 32];
    __shared__ u16 lB[64 * 32];
    const int tid = threadIdx.x;
    const int lane = tid & 63;
    const int wv = tid >> 6;
    const int wmi = wv >> 1, wni = wv & 1;
    const int g = lane >> 4, ln = lane & 15;
    const int bm0 = blockIdx.y * 64, bn0 = blockIdx.x * 64;
    const int srow = tid >> 2, sseg = tid & 3;
    f32x4 acc[2][2] = {};
    for (int k0 = 0; k0 < 1024; k0 += 32) {
        *(i32x4*)&lA[srow * 32 + sseg * 8] =
            *(const i32x4*)&A[(size_t)(bm0 + srow) * 1024 + k0 + sseg * 8];
        *(i32x4*)&lB[srow * 32 + sseg * 8] =
            *(const i32x4*)&Bt[(size_t)(bn0 + srow) * 1024 + k0 + sseg * 8];
        __syncthreads();
        bf16x8 aF[2], bF[2];
#pragma unroll
        for (int mf = 0; mf < 2; ++mf)
            aF[mf] = *(const bf16x8*)&lA[(wmi * 32 + mf * 16 + ln) * 32 + g * 8];
#pragma unroll
        for (int nf = 0; nf < 2; ++nf)
            bF[nf] = *(const bf16x8*)&lB[(wni * 32 + nf * 16 + ln) * 32 + g * 8];
#pragma unroll
        for (int mf = 0; mf < 2; ++mf)
#pragma unroll
            for (int nf = 0; nf < 2; ++nf)
                acc[mf][nf] = __builtin_amdgcn_mfma_f32_16x16x32_bf16(
                    aF[mf], bF[nf], acc[mf][nf], 0, 0, 0);
        __syncthreads();
    }
#pragma unroll
    for (int mf = 0; mf < 2; ++mf)
#pragma unroll
        for (int nf = 0; nf < 2; ++nf)
#pragma unroll
            for (int r = 0; r < 4; ++r) {
                int grow = bm0 + wmi * 32 + mf * 16 + g * 4 + r;
                int gcol = bn0 + wni * 32 + nf * 16 + ln;
                out[(size_t)grow * 256 + gcol] = acc[mf][nf][r] + bias[gcol];
            }
}

// ---------- row L2-normalize: e fp32 [1024][256] -> e_b bf16 ----------
__global__ __launch_bounds__(256) void normalize_kernel(const float* __restrict__ e,
                                                        u16* __restrict__ eb) {
    __shared__ float sw[4];
    int row = blockIdx.x, tid = threadIdx.x;
    float v = e[row * 256 + tid];
    float ss = v * v;
#pragma unroll
    for (int m = 32; m; m >>= 1) ss += __shfl_xor(ss, m, 64);
    if ((tid & 63) == 0) sw[tid >> 6] = ss;
    __syncthreads();
    float tot = sw[0] + sw[1] + sw[2] + sw[3];
    float inv = 1.0f / sqrtf(tot);
    eb[row * 256 + tid] = f2bf(v * inv);
}

// ---------- pairwise logits (padded LDS rows: 129 words -> 2-way max conflict) ----------
__global__ __launch_bounds__(256) void pairwise_kernel(const u16* __restrict__ eb,
                                                       const float* __restrict__ wm,
                                                       const float* __restrict__ bmp,
                                                       float* __restrict__ out) {
    int ib = blockIdx.y, jb = blockIdx.x;
    if (jb < ib) return;
    __shared__ u32 sI[64 * 129];
    __shared__ u32 sJ[64 * 129];
    __shared__ float swm[256];
    int tid = threadIdx.x;
    {
        const u32* srcI = (const u32*)(eb + (size_t)ib * 64 * 256);
        const u32* srcJ = (const u32*)(eb + (size_t)jb * 64 * 256);
#pragma unroll
        for (int q = 0; q < 32; ++q) {
            int idx = q * 256 + tid;
            int rr = idx >> 7, cc = idx & 127;
            sI[rr * 129 + cc] = srcI[idx];
            sJ[rr * 129 + cc] = srcJ[idx];
        }
        swm[tid] = wm[tid];
    }
    __syncthreads();
    float bmv = bmp[0];
    int tx = tid & 15, ty = tid >> 4;
    float acc[4][4] = {};
    for (int kk = 0; kk < 128; ++kk) {
        float w0 = swm[kk * 2], w1 = swm[kk * 2 + 1];
        float li[4], hi[4], lj[4], hj[4];
#pragma unroll
        for (int a = 0; a < 4; ++a) {
            u32 u = sI[(ty * 4 + a) * 129 + kk];
            li[a] = __uint_as_float(u << 16);
            hi[a] = __uint_as_float(u & 0xFFFF0000u);
        }
#pragma unroll
        for (int b = 0; b < 4; ++b) {
            u32 u = sJ[(tx * 4 + b) * 129 + kk];
            lj[b] = __uint_as_float(u << 16);
            hj[b] = __uint_as_float(u & 0xFFFF0000u);
        }
#pragma unroll
        for (int a = 0; a < 4; ++a)
#pragma unroll
            for (int b = 0; b < 4; ++b)
                acc[a][b] += w0 * fabsf(li[a] - lj[b]) + w1 * fabsf(hi[a] - hj[b]);
    }
#pragma unroll
    for (int a = 0; a < 4; ++a) {
        int i = ib * 64 + ty * 4 + a;
#pragma unroll
        for (int b = 0; b < 4; ++b) {
            int j = jb * 64 + tx * 4 + b;
            if (j > i) {
                int p = i * (2047 - i) / 2 + (j - i - 1);
                out[p] = acc[a][b] + bmv;
            }
        }
    }
}

extern "C" void kernel_launch(void* const* d_in, const int* in_sizes, int n_in,
                              void* d_out, int out_size, void* d_ws, size_t ws_size,
                              hipStream_t stream) {
    const float* features = (const float*)d_in[0];
    const float* conv_w = (const float*)d_in[2];
    const float* conv_b = (const float*)d_in[3];
    const float* w1 = (const float*)d_in[4];
    const float* b1 = (const float*)d_in[5];
    const float* w2 = (const float*)d_in[6];
    const float* b2 = (const float*)d_in[7];
    const float* wm = (const float*)d_in[8];
    const float* bm = (const float*)d_in[9];
    float* logits = (float*)d_out;

    char* ws = (char*)d_ws;
    u16* x_b = (u16*)(ws);                       // 25,690,112
    u16* w1t = (u16*)(ws + 25690112);            // 25,690,112
    float* part = (float*)(ws + 51380224);       // 16,777,216
    u16* h_b = (u16*)(ws + 68157440);            // 2,097,152
    u16* w2t = (u16*)(ws + 70254592);            // 524,288
    u16* cwb = (u16*)(ws + 70778880);            // 1,179,648
    float* e = (float*)(ws + 71958528);          // 1,048,576
    u16* e_b = (u16*)(ws + 73007104);            // 524,288
    u16* col = (u16*)(ws + 73531392);            // variable (im2col chunk)

    // conv chunking: unit = 128 images = 6272 rows = 28,901,376 B of col
    const size_t tail = 73531392;
    const size_t unit = (size_t)6272 * 2304 * 2;
    size_t avail = (ws_size > tail) ? (ws_size - tail) : 0;
    size_t units = avail / unit;
    int cimgs = (units >= 8) ? 1024 : (units >= 4) ? 512 : (units >= 2) ? 256 : 128;

    // weight prep
    wreorder_kernel<<<256, 256, 0, stream>>>(conv_w, cwb);
    transpose_cast_kernel<<<dim3(32, 392), 256, 0, stream>>>(w1, w1t, 12544, 1024);
    transpose_cast_kernel<<<dim3(8, 32), 256, 0, stream>>>(w2, w2t, 1024, 256);

    // conv: per chunk, im2col then 128^2 GEMM (M=cimgs*49, N=256, K=2304)
    for (int img0 = 0; img0 < 1024; img0 += cimgs) {
        im2col_kernel<<<cimgs * 7, 256, 0, stream>>>(features, col, img0);
        gemm128_kernel<0><<<dim3(2, (cimgs / 128) * 49), 256, 0, stream>>>(
            col, 2304, cwb, 2304, conv_b, x_b, img0 * 49, 2304);
    }

    // FC1: split-K=4 partials then reduce (+bias, ReLU)
    gemm128_kernel<1><<<dim3(8, 8, 4), 256, 0, stream>>>(
        x_b, 12544, w1t, 12544, nullptr, part, 0, 3136);
    fc1_reduce_kernel<<<4096, 256, 0, stream>>>(part, b1, h_b);

    // FC2 + normalize + pairwise
    gemm64_fc2<<<dim3(4, 16), 256, 0, stream>>>(h_b, w2t, b2, e);
    normalize_kernel<<<1024, 256, 0, stream>>>(e, e_b);
    pairwise_kernel<<<dim3(16, 16), 256, 0, stream>>>(e_b, wm, bm, logits);
}

// Round 4
// 659.483 us; speedup vs baseline: 1.6972x; 1.0233x over previous
//
#include <hip/hip_runtime.h>
#include <cstdint>
#include <cstddef>

// MatchNet pipeline on MI355X (gfx950), round 3.
// R2 post-mortem: conv GEMM 155us with MfmaUtil 15 / VALU 16 / HBM 21 / Occ 17%
// -> latency-bound (per-K-step vmcnt(0) drain, HBM-streamed A, no reuse).
// R3: (a) 2-phase double-buffered global_load_lds prefetch in the 128^2 GEMM
// (T3 minimum pipeline: stage t+1 before computing t, ONE barrier per step);
// (b) FC1 split-K 4 -> 14 (896 blocks = 3.5/CU), partials aliased on dead col.
//
// ws layout: x_b | w1t | h_b | w2t | cwb | e | e_b | col (conv chunk; FC1
// partials alias col after conv completes)

using u16 = unsigned short;
using u32 = unsigned int;
typedef __attribute__((ext_vector_type(8))) short bf16x8;
typedef __attribute__((ext_vector_type(4))) float f32x4;
typedef __attribute__((ext_vector_type(4))) int i32x4;

__device__ __forceinline__ u16 f2bf(float f) {
    u32 u = __float_as_uint(f);
    u32 r = (u + 0x7FFFu + ((u >> 16) & 1u)) >> 16;   // RNE
    return (u16)r;
}

__device__ __forceinline__ void gload_lds16(const u16* gsrc, u16* ldst) {
    __builtin_amdgcn_global_load_lds(
        (const __attribute__((address_space(1))) u32*)gsrc,
        (__attribute__((address_space(3))) u32*)ldst,
        16, 0, 0);
}

// ---------- weight reorder: conv_w [oc][c][3][3] fp32 -> cwb [oc][tap*256+c] bf16 ----------
__global__ __launch_bounds__(256) void wreorder_kernel(const float* __restrict__ w,
                                                       u16* __restrict__ out) {
    int idx = blockIdx.x * 256 + threadIdx.x;   // oc*256 + c
    int oc = idx >> 8, c = idx & 255;
    const float* src = w + (size_t)idx * 9;
    u16* dst = out + (size_t)oc * 2304 + c;
#pragma unroll
    for (int t = 0; t < 9; ++t) dst[t * 256] = f2bf(src[t]);
}

// ---------- transpose + cast: in fp32 [R][C] -> out bf16 [C][R]; R,C % 32 == 0 ----------
__global__ __launch_bounds__(256) void transpose_cast_kernel(const float* __restrict__ in,
                                                             u16* __restrict__ out,
                                                             int R, int C) {
    __shared__ float t[32][33];
    int tx = threadIdx.x & 31, ty = threadIdx.x >> 5;  // 32 x 8
    int r0 = blockIdx.y * 32, c0 = blockIdx.x * 32;
#pragma unroll
    for (int p = 0; p < 4; ++p)
        t[ty + p * 8][tx] = in[(size_t)(r0 + ty + p * 8) * C + c0 + tx];
    __syncthreads();
#pragma unroll
    for (int p = 0; p < 4; ++p)
        out[(size_t)(c0 + ty + p * 8) * R + r0 + tx] = f2bf(t[tx][ty + p * 8]);
}

// ---------- im2col (tap-major): col[m_local][tap*256+c], m=(n,oy,ox) ----------
__global__ __launch_bounds__(256) void im2col_kernel(const float* __restrict__ features,
                                                     u16* __restrict__ col, int n_base) {
    int blk = blockIdx.x;
    int n_local = blk / 7, oy = blk - n_local * 7;
    int n = n_base + n_local;
    int c = threadIdx.x;
    const float* f = features + ((size_t)n * 256 + c) * 196;
    float r[3][16];
#pragma unroll
    for (int dy = 0; dy < 3; ++dy) {
        int iy = oy * 2 - 1 + dy;
        r[dy][0] = 0.f;
        r[dy][15] = 0.f;
        if ((unsigned)iy < 14u) {
            const float* row = f + iy * 14;
#pragma unroll
            for (int x = 0; x < 7; ++x) {
                float2 v = *(const float2*)(row + x * 2);
                r[dy][1 + x * 2] = v.x;
                r[dy][2 + x * 2] = v.y;
            }
        } else {
#pragma unroll
            for (int x = 0; x < 14; ++x) r[dy][1 + x] = 0.f;
        }
    }
    u16* base = col + (size_t)(n_local * 49 + oy * 7) * 2304 + c;
#pragma unroll
    for (int dy = 0; dy < 3; ++dy)
#pragma unroll
        for (int dx = 0; dx < 3; ++dx) {
            int tap = dy * 3 + dx;
#pragma unroll
            for (int ox = 0; ox < 7; ++ox)   // ix+1 = ox*2+dx
                base[(size_t)ox * 2304 + tap * 256] = f2bf(r[dy][ox * 2 + dx]);
        }
}

// ---------- 128x128 GEMM, BK=64, 2-phase dbuf global_load_lds, 4 waves 4x4 frags ----------
// MODE 0: conv epilogue (+bias, ReLU, bf16 scatter to x_b [n][oc*49+s])
// MODE 1: fc1 split-K partial (fp32; out += blockIdx.z * 1M elems)
template <int MODE>
__global__ __launch_bounds__(256) void gemm128_kernel(
    const u16* __restrict__ A, int lda,
    const u16* __restrict__ Bt, int ldb,
    const float* __restrict__ bias,
    void* __restrict__ out,
    int m_base, int k_chunk)
{
    __shared__ __align__(16) u16 sA[2][128 * 64];
    __shared__ __align__(16) u16 sB[2][128 * 64];
    const int tid = threadIdx.x;
    const int lane = tid & 63;
    const int g = lane >> 4, ln = lane & 15;
    const int wv = tid >> 6;
    const int wm2 = wv >> 1, wn2 = wv & 1;
    const int bm0 = blockIdx.y * 128, bn0 = blockIdx.x * 128;
    const int srow = tid >> 3;          // 0..31
    const int scol = (tid & 7) * 8;     // 0,8,..,56
    const int k_begin = (MODE == 1) ? blockIdx.z * k_chunk : 0;

    const u16* Ab = A + (size_t)bm0 * lda + k_begin + scol;
    const u16* Bb = Bt + (size_t)bn0 * ldb + k_begin + scol;
    const int nsteps = k_chunk >> 6;

    f32x4 acc[4][4] = {};

    // prologue: stage step 0 into buf 0
#pragma unroll
    for (int q = 0; q < 4; ++q) {
        int row = q * 32 + srow;
        gload_lds16(Ab + (size_t)row * lda, &sA[0][(q * 256 + tid) * 8]);
        gload_lds16(Bb + (size_t)row * ldb, &sB[0][(q * 256 + tid) * 8]);
    }
    __syncthreads();   // implicit vmcnt(0): tile 0 landed

    for (int t = 0; t < nsteps; ++t) {
        const int cur = t & 1;
        if (t + 1 < nsteps) {
            const int k0 = (t + 1) << 6;
#pragma unroll
            for (int q = 0; q < 4; ++q) {
                int row = q * 32 + srow;
                gload_lds16(Ab + (size_t)row * lda + k0, &sA[cur ^ 1][(q * 256 + tid) * 8]);
                gload_lds16(Bb + (size_t)row * ldb + k0, &sB[cur ^ 1][(q * 256 + tid) * 8]);
            }
        }
        const u16* bufA = sA[cur];
        const u16* bufB = sB[cur];
#pragma unroll
        for (int ks = 0; ks < 2; ++ks) {
            bf16x8 aF[4], bF[4];
#pragma unroll
            for (int i = 0; i < 4; ++i)
                aF[i] = *(const bf16x8*)&bufA[(wm2 * 64 + i * 16 + ln) * 64 + ks * 32 + g * 8];
#pragma unroll
            for (int i = 0; i < 4; ++i)
                bF[i] = *(const bf16x8*)&bufB[(wn2 * 64 + i * 16 + ln) * 64 + ks * 32 + g * 8];
#pragma unroll
            for (int mf = 0; mf < 4; ++mf)
#pragma unroll
                for (int nf = 0; nf < 4; ++nf)
                    acc[mf][nf] = __builtin_amdgcn_mfma_f32_16x16x32_bf16(
                        aF[mf], bF[nf], acc[mf][nf], 0, 0, 0);
        }
        if (t + 1 < nsteps) __syncthreads();  // vmcnt(0): prefetch landed; all waves done with cur
    }

    if (MODE == 0) {
        u16* xb = (u16*)out;
#pragma unroll
        for (int mf = 0; mf < 4; ++mf)
#pragma unroll
            for (int nf = 0; nf < 4; ++nf)
#pragma unroll
                for (int r = 0; r < 4; ++r) {
                    int grow = m_base + bm0 + wm2 * 64 + mf * 16 + g * 4 + r;
                    int gcol = bn0 + wn2 * 64 + nf * 16 + ln;
                    float v = fmaxf(acc[mf][nf][r] + bias[gcol], 0.f);
                    int n = grow / 49, s = grow - n * 49;
                    xb[(size_t)n * 12544 + gcol * 49 + s] = f2bf(v);
                }
    } else {
        float* po = (float*)out + (size_t)blockIdx.z * (1024 * 1024);
#pragma unroll
        for (int mf = 0; mf < 4; ++mf)
#pragma unroll
            for (int nf = 0; nf < 4; ++nf)
#pragma unroll
                for (int r = 0; r < 4; ++r) {
                    int grow = bm0 + wm2 * 64 + mf * 16 + g * 4 + r;
                    int gcol = bn0 + wn2 * 64 + nf * 16 + ln;
                    po[(size_t)grow * 1024 + gcol] = acc[mf][nf][r];
                }
    }
}

// ---------- FC1 reduce: sum splitK partials + bias + ReLU -> bf16 ----------
__global__ __launch_bounds__(256) void fc1_reduce_kernel(const float* __restrict__ part,
                                                         const float* __restrict__ b1,
                                                         u16* __restrict__ h, int splitK) {
    int i = blockIdx.x * 256 + threadIdx.x;
    float v = 0.f;
    for (int s = 0; s < splitK; ++s) v += part[i + (size_t)s * 1048576];
    v = fmaxf(v + b1[i & 1023], 0.f);
    h[i] = f2bf(v);
}

// ---------- FC2: 64x64 tile (M=1024,N=256,K=1024), fp32 out +bias ----------
__global__ __launch_bounds__(256) void gemm64_fc2(const u16* __restrict__ A,
                                                  const u16* __restrict__ Bt,
                                                  const float* __restrict__ bias,
                                                  float* __restrict__ out) {
    __shared__ u16 lA[64 * 32];
    __shared__ u16 lB[64 * 32];
    const int tid = threadIdx.x;
    const int lane = tid & 63;
    const int wv = tid >> 6;
    const int wmi = wv >> 1, wni = wv & 1;
    const int g = lane >> 4, ln = lane & 15;
    const int bm0 = blockIdx.y * 64, bn0 = blockIdx.x * 64;
    const int srow = tid >> 2, sseg = tid & 3;
    f32x4 acc[2][2] = {};
    for (int k0 = 0; k0 < 1024; k0 += 32) {
        *(i32x4*)&lA[srow * 32 + sseg * 8] =
            *(const i32x4*)&A[(size_t)(bm0 + srow) * 1024 + k0 + sseg * 8];
        *(i32x4*)&lB[srow * 32 + sseg * 8] =
            *(const i32x4*)&Bt[(size_t)(bn0 + srow) * 1024 + k0 + sseg * 8];
        __syncthreads();
        bf16x8 aF[2], bF[2];
#pragma unroll
        for (int mf = 0; mf < 2; ++mf)
            aF[mf] = *(const bf16x8*)&lA[(wmi * 32 + mf * 16 + ln) * 32 + g * 8];
#pragma unroll
        for (int nf = 0; nf < 2; ++nf)
            bF[nf] = *(const bf16x8*)&lB[(wni * 32 + nf * 16 + ln) * 32 + g * 8];
#pragma unroll
        for (int mf = 0; mf < 2; ++mf)
#pragma unroll
            for (int nf = 0; nf < 2; ++nf)
                acc[mf][nf] = __builtin_amdgcn_mfma_f32_16x16x32_bf16(
                    aF[mf], bF[nf], acc[mf][nf], 0, 0, 0);
        __syncthreads();
    }
#pragma unroll
    for (int mf = 0; mf < 2; ++mf)
#pragma unroll
        for (int nf = 0; nf < 2; ++nf)
#pragma unroll
            for (int r = 0; r < 4; ++r) {
                int grow = bm0 + wmi * 32 + mf * 16 + g * 4 + r;
                int gcol = bn0 + wni * 32 + nf * 16 + ln;
                out[(size_t)grow * 256 + gcol] = acc[mf][nf][r] + bias[gcol];
            }
}

// ---------- row L2-normalize: e fp32 [1024][256] -> e_b bf16 ----------
__global__ __launch_bounds__(256) void normalize_kernel(const float* __restrict__ e,
                                                        u16* __restrict__ eb) {
    __shared__ float sw[4];
    int row = blockIdx.x, tid = threadIdx.x;
    float v = e[row * 256 + tid];
    float ss = v * v;
#pragma unroll
    for (int m = 32; m; m >>= 1) ss += __shfl_xor(ss, m, 64);
    if ((tid & 63) == 0) sw[tid >> 6] = ss;
    __syncthreads();
    float tot = sw[0] + sw[1] + sw[2] + sw[3];
    float inv = 1.0f / sqrtf(tot);
    eb[row * 256 + tid] = f2bf(v * inv);
}

// ---------- pairwise logits (padded LDS rows: 129 words) ----------
__global__ __launch_bounds__(256) void pairwise_kernel(const u16* __restrict__ eb,
                                                       const float* __restrict__ wm,
                                                       const float* __restrict__ bmp,
                                                       float* __restrict__ out) {
    int ib = blockIdx.y, jb = blockIdx.x;
    if (jb < ib) return;
    __shared__ u32 sI[64 * 129];
    __shared__ u32 sJ[64 * 129];
    __shared__ float swm[256];
    int tid = threadIdx.x;
    {
        const u32* srcI = (const u32*)(eb + (size_t)ib * 64 * 256);
        const u32* srcJ = (const u32*)(eb + (size_t)jb * 64 * 256);
#pragma unroll
        for (int q = 0; q < 32; ++q) {
            int idx = q * 256 + tid;
            int rr = idx >> 7, cc = idx & 127;
            sI[rr * 129 + cc] = srcI[idx];
            sJ[rr * 129 + cc] = srcJ[idx];
        }
        swm[tid] = wm[tid];
    }
    __syncthreads();
    float bmv = bmp[0];
    int tx = tid & 15, ty = tid >> 4;
    float acc[4][4] = {};
    for (int kk = 0; kk < 128; ++kk) {
        float w0 = swm[kk * 2], w1 = swm[kk * 2 + 1];
        float li[4], hi[4], lj[4], hj[4];
#pragma unroll
        for (int a = 0; a < 4; ++a) {
            u32 u = sI[(ty * 4 + a) * 129 + kk];
            li[a] = __uint_as_float(u << 16);
            hi[a] = __uint_as_float(u & 0xFFFF0000u);
        }
#pragma unroll
        for (int b = 0; b < 4; ++b) {
            u32 u = sJ[(tx * 4 + b) * 129 + kk];
            lj[b] = __uint_as_float(u << 16);
            hj[b] = __uint_as_float(u & 0xFFFF0000u);
        }
#pragma unroll
        for (int a = 0; a < 4; ++a)
#pragma unroll
            for (int b = 0; b < 4; ++b)
                acc[a][b] += w0 * fabsf(li[a] - lj[b]) + w1 * fabsf(hi[a] - hj[b]);
    }
#pragma unroll
    for (int a = 0; a < 4; ++a) {
        int i = ib * 64 + ty * 4 + a;
#pragma unroll
        for (int b = 0; b < 4; ++b) {
            int j = jb * 64 + tx * 4 + b;
            if (j > i) {
                int p = i * (2047 - i) / 2 + (j - i - 1);
                out[p] = acc[a][b] + bmv;
            }
        }
    }
}

extern "C" void kernel_launch(void* const* d_in, const int* in_sizes, int n_in,
                              void* d_out, int out_size, void* d_ws, size_t ws_size,
                              hipStream_t stream) {
    const float* features = (const float*)d_in[0];
    const float* conv_w = (const float*)d_in[2];
    const float* conv_b = (const float*)d_in[3];
    const float* w1 = (const float*)d_in[4];
    const float* b1 = (const float*)d_in[5];
    const float* w2 = (const float*)d_in[6];
    const float* b2 = (const float*)d_in[7];
    const float* wm = (const float*)d_in[8];
    const float* bm = (const float*)d_in[9];
    float* logits = (float*)d_out;

    char* ws = (char*)d_ws;
    u16* x_b = (u16*)(ws);                       // 25,690,112
    u16* w1t = (u16*)(ws + 25690112);            // 25,690,112
    u16* h_b = (u16*)(ws + 51380224);            // 2,097,152
    u16* w2t = (u16*)(ws + 53477376);            // 524,288
    u16* cwb = (u16*)(ws + 54001664);            // 1,179,648
    float* e = (float*)(ws + 55181312);          // 1,048,576
    u16* e_b = (u16*)(ws + 56229888);            // 524,288
    u16* col = (u16*)(ws + 56754176);            // conv chunk (FC1 partials alias)
    float* part = (float*)col;                   // valid after conv completes

    // conv chunking: unit = 128 images = 6272 rows = 28,901,376 B of col
    const size_t tail = 56754176;
    const size_t unit = (size_t)6272 * 2304 * 2;
    size_t avail = (ws_size > tail) ? (ws_size - tail) : 0;
    size_t units = avail / unit;
    int cimgs = (units >= 8) ? 1024 : (units >= 4) ? 512 : (units >= 2) ? 256 : 128;
    size_t colbytes = (size_t)cimgs * 49 * 2304 * 2;
    // FC1 split-K: partials (splitK * 4MB fp32) must fit in the col region
    int splitK = (colbytes >= (size_t)14 * 4194304) ? 14 : 7;   // both divide 196 K-steps
    int kchunk = 12544 / splitK;                                 // 896 or 1792

    // weight prep
    wreorder_kernel<<<256, 256, 0, stream>>>(conv_w, cwb);
    transpose_cast_kernel<<<dim3(32, 392), 256, 0, stream>>>(w1, w1t, 12544, 1024);
    transpose_cast_kernel<<<dim3(8, 32), 256, 0, stream>>>(w2, w2t, 1024, 256);

    // conv: per chunk, im2col then 128^2 GEMM (M=cimgs*49, N=256, K=2304)
    for (int img0 = 0; img0 < 1024; img0 += cimgs) {
        im2col_kernel<<<cimgs * 7, 256, 0, stream>>>(features, col, img0);
        gemm128_kernel<0><<<dim3(2, (cimgs / 128) * 49), 256, 0, stream>>>(
            col, 2304, cwb, 2304, conv_b, x_b, img0 * 49, 2304);
    }

    // FC1: split-K partials then reduce (+bias, ReLU)
    gemm128_kernel<1><<<dim3(8, 8, splitK), 256, 0, stream>>>(
        x_b, 12544, w1t, 12544, nullptr, part, 0, kchunk);
    fc1_reduce_kernel<<<4096, 256, 0, stream>>>(part, b1, h_b, splitK);

    // FC2 + normalize + pairwise
    gemm64_fc2<<<dim3(4, 16), 256, 0, stream>>>(h_b, w2t, b2, e);
    normalize_kernel<<<1024, 256, 0, stream>>>(e, e_b);
    pairwise_kernel<<<dim3(16, 16), 256, 0, stream>>>(e_b, wm, bm, logits);
}